// Round 3
// baseline (416.449 us; speedup 1.0000x reference)
//
#include <hip/hip_runtime.h>
#include <stdint.h>

typedef __attribute__((ext_vector_type(4))) int int4v;
typedef __attribute__((ext_vector_type(16))) int int16v;
typedef __attribute__((ext_vector_type(4))) uint32_t uint4v;

#define M_DIM 8192
#define N_DIM 4096
#define K_DIM 4096

// K-permuted layout: within each 64-byte K chunk, stored byte p holds
// original k = (p>>2) + 16*(p&3). Applied identically to A and B => MFMA
// dot products unchanged. GEMM XOR-swizzles 16-B slots within each 64-B
// LDS row (slot = sIdx ^ (row&3)); swizzle applied in the global source
// address at staging and inverted at fragment-read time.

// ---------------- pack x: int32 -> int8, K-permuted ----------------
__global__ void pack_a_perm(const int* __restrict__ x, uint4v* __restrict__ a8) {
    const int g = blockIdx.x * blockDim.x + threadIdx.x;  // global 16-B word index
    const int w0 = (g & 3) * 4;                           // word slot within chunk
    const int chunk = g >> 2;                             // 64-element k chunk
    const int* base = x + (size_t)chunk * 64;
    int4v L[4];
#pragma unroll
    for (int j = 0; j < 4; ++j) L[j] = *(const int4v*)(base + j * 16 + w0);
    uint4v outv;
#pragma unroll
    for (int wi = 0; wi < 4; ++wi) {
        outv[wi] = (uint32_t)(L[0][wi] & 0xff) | ((uint32_t)(L[1][wi] & 0xff) << 8) |
                   ((uint32_t)(L[2][wi] & 0xff) << 16) | ((uint32_t)(L[3][wi] & 0xff) << 24);
    }
    a8[g] = outv;
}

// ------- transpose+pack weight: [K][N] int32 -> Bt[N][K-permuted] int8 -------
__global__ void transpose_b_perm(const int* __restrict__ w, int8_t* __restrict__ bt) {
    const int t = threadIdx.x;
    const int kt = blockIdx.y * 64;
    const int n0 = blockIdx.x * 64;
    const int c4 = t & 3;
    const int n = t >> 2;
    const int w0 = c4 * 4;
    const int* col = w + (size_t)kt * N_DIM + n0 + n;
    uint4v outv;
#pragma unroll
    for (int wi = 0; wi < 4; ++wi) {
        uint32_t p = 0;
#pragma unroll
        for (int j = 0; j < 4; ++j) {
            uint32_t b = (uint32_t)(col[(size_t)(w0 + wi + 16 * j) * N_DIM] & 0xff);
            p |= b << (8 * j);
        }
        outv[wi] = p;
    }
    *(uint4v*)&bt[(size_t)(n0 + n) * K_DIM + kt + w0 * 4] = outv;
}

// -------- GEMM: 256x256 tile, BK=64, 4-buffer deep pipeline --------
__device__ inline void async16(const void* g, void* l) {
    __builtin_amdgcn_global_load_lds(
        (const __attribute__((address_space(1))) uint32_t*)g,
        (__attribute__((address_space(3))) uint32_t*)l, 16, 0, 0);
}

#define SB() __builtin_amdgcn_sched_barrier(0)
#define BAR() do { SB(); __builtin_amdgcn_s_barrier(); SB(); } while (0)

__global__ void __launch_bounds__(512, 2)
gemm_kernel(const int8_t* __restrict__ A, const int8_t* __restrict__ Bt,
            const float* __restrict__ pa, const float* __restrict__ pb,
            int* __restrict__ out) {
    // 4 buffers x 32 KiB: buf b at b*32768, A-tile 16K @ +0, B-tile 16K @ +16384.
    __shared__ int8_t smem[131072];

    const int t = threadIdx.x;
    const int lane = t & 63;
    const int wave = t >> 6;

    // XCD-aware bijective swizzle (nwg = 512, divisible by 8)
    int wg = (int)blockIdx.x;
    wg = (wg & 7) * 64 + (wg >> 3);
    const int bx = wg & 15;         // N / 256 = 16
    const int by = wg >> 4;         // M / 256 = 32
    const int m0 = by * 256;
    const int n0 = bx * 256;

    const int wm = (wave >> 2) * 128;   // 2 waves along M
    const int wn = (wave & 3) * 64;     // 4 waves along N
    const float scale = pa[0] * pb[0];

    // ---- staging (linear LDS dest; swizzle folded into global src) ----
    // 512 threads cover one 128-row x 64-B chunk per issue: 4 threads/row.
    const int srow = wave * 16 + (lane >> 2);            // row within chunk
    const int gx = ((lane & 3) ^ (srow & 3)) * 16;       // pre-swizzled slot
    const int8_t* pA0 = A + (size_t)(m0 + srow) * K_DIM + gx;
    const int8_t* pA1 = A + (size_t)(m0 + 128 + srow) * K_DIM + gx;
    const int8_t* pB0 = Bt + (size_t)(n0 + srow) * K_DIM + gx;
    const int8_t* pB1 = Bt + (size_t)(n0 + 128 + srow) * K_DIM + gx;
    const int ldsA0 = wave * 1024;                 // wave-uniform dests
    const int ldsA1 = 8192 + wave * 1024;
    const int ldsB0 = 16384 + wave * 1024;
    const int ldsB1 = 16384 + 8192 + wave * 1024;

    // ---- fragment-read constants ----
    const int rl = lane & 31;
    const int hl = lane >> 5;          // 16-B half within K=32 MFMA window
    const int xl = lane & 3;           // == row&3 for every row this lane reads
    const int koffE = (hl ^ xl) * 16;          // k-window 0 slots {0,1}
    const int koffO = ((2 + hl) ^ xl) * 16;    // k-window 1 slots {2,3}
    const int raBase = (wm + rl) * 64;
    const int rbBase = 16384 + (wn + rl) * 64;

    int16v acc[4][2];
#pragma unroll
    for (int mi = 0; mi < 4; ++mi)
#pragma unroll
        for (int j = 0; j < 2; ++j)
#pragma unroll
            for (int r = 0; r < 16; ++r) acc[mi][j][r] = 0;

    int4v afE[4], bfE[2], afO[4], bfO[2];

#define STAGE(TT) do {                                                   \
        const int b_ = ((TT) & 3) * 32768;                               \
        const int kt_ = ((TT) & 63) * 64;   /* wrap: dead restage */     \
        async16(pA0 + kt_, smem + b_ + ldsA0);                           \
        async16(pA1 + kt_, smem + b_ + ldsA1);                           \
        async16(pB0 + kt_, smem + b_ + ldsB0);                           \
        async16(pB1 + kt_, smem + b_ + ldsB1);                           \
    } while (0)

#define RD_SET(AF, BF, BUF, KOFF) do {                                   \
        const int ab_ = (BUF) * 32768;                                   \
        AF[0] = *(const int4v*)&smem[ab_ + raBase + 0 * 2048 + (KOFF)];  \
        AF[1] = *(const int4v*)&smem[ab_ + raBase + 1 * 2048 + (KOFF)];  \
        AF[2] = *(const int4v*)&smem[ab_ + raBase + 2 * 2048 + (KOFF)];  \
        AF[3] = *(const int4v*)&smem[ab_ + raBase + 3 * 2048 + (KOFF)];  \
        BF[0] = *(const int4v*)&smem[ab_ + rbBase + 0 * 2048 + (KOFF)];  \
        BF[1] = *(const int4v*)&smem[ab_ + rbBase + 1 * 2048 + (KOFF)];  \
    } while (0)

#define MM(AF, BF) do {                                                  \
        __builtin_amdgcn_s_setprio(1);                                   \
        _Pragma("unroll")                                                \
        for (int mi = 0; mi < 4; ++mi)                                   \
            _Pragma("unroll")                                            \
            for (int j = 0; j < 2; ++j)                                  \
                acc[mi][j] = __builtin_amdgcn_mfma_i32_32x32x32_i8(      \
                    AF[mi], BF[j], acc[mi][j], 0, 0, 0);                 \
        __builtin_amdgcn_s_setprio(0);                                   \
    } while (0)

    // ---- prologue: 3 tiles in flight ----
    STAGE(0); STAGE(1); STAGE(2);
    asm volatile("s_waitcnt vmcnt(8)" ::: "memory");   // tile 0 (mine) landed
    BAR();                                             // => everyone's tile 0 landed
    RD_SET(afE, bfE, 0, koffE);                        // frags(0, k0)

    // Steady state per tile tt: vmcnt(8) retires tile tt+1, issued at tile
    // tt-2 (~2.3 tiles of latency cover). Every MFMA cluster runs with the
    // next half-phase's 6 ds_reads in flight (counted lgkm, never 0).
#pragma unroll 1
    for (int tt = 0; tt < 64; ++tt) {
        STAGE(tt + 3);                                 // buf of tile tt-1: free
        RD_SET(afO, bfO, tt & 3, koffO);               // frags(tt, k1)
        SB();
        MM(afE, bfE);                                  // (tt, k0)
        SB();
        asm volatile("s_waitcnt vmcnt(8)" ::: "memory");   // tile tt+1 (mine)
        BAR();                                         // => everyone's tt+1 landed
        RD_SET(afE, bfE, (tt + 1) & 3, koffE);         // frags(tt+1, k0); dead junk at tt=63
        SB();
        MM(afO, bfO);                                  // (tt, k1)
        BAR();
    }

    // Drain: no DMA/DS may outlive the workgroup (next block reuses this LDS).
    asm volatile("s_waitcnt vmcnt(0) lgkmcnt(0)" ::: "memory");

    // ---- epilogue: dequant + saturate + store ----
    const int col = lane & 31;
    const int rbase = (lane >> 5) * 4;
#pragma unroll
    for (int mi = 0; mi < 4; ++mi)
#pragma unroll
        for (int j = 0; j < 2; ++j)
#pragma unroll
            for (int r = 0; r < 16; ++r) {
                const int rowf = rbase + (r & 3) + 8 * (r >> 2);
                float v = (float)acc[mi][j][r] * scale;
                v = rintf(v);
                v = fminf(127.f, fmaxf(-128.f, v));
                out[(size_t)(m0 + wm + mi * 32 + rowf) * N_DIM +
                    (n0 + wn + j * 32 + col)] = (int)v;
            }
#undef STAGE
#undef RD_SET
#undef MM
}

extern "C" void kernel_launch(void* const* d_in, const int* in_sizes, int n_in,
                              void* d_out, int out_size, void* d_ws, size_t ws_size,
                              hipStream_t stream) {
    const int* x = (const int*)d_in[0];
    const int* w = (const int*)d_in[1];
    const float* pa = (const float*)d_in[2];
    const float* pb = (const float*)d_in[3];
    int* out = (int*)d_out;

    int8_t* a8 = (int8_t*)d_ws;                       // 32 MiB
    int8_t* bt8 = a8 + (size_t)M_DIM * K_DIM;         // 16 MiB

    const int nwords_a = M_DIM * K_DIM / 16;
    pack_a_perm<<<nwords_a / 256, 256, 0, stream>>>(x, (uint4v*)a8);
    transpose_b_perm<<<dim3(N_DIM / 64, K_DIM / 64), 256, 0, stream>>>(w, bt8);
    gemm_kernel<<<dim3(512), dim3(512), 0, stream>>>(a8, bt8, pa, pb, out);
}